// Round 1
// baseline (2229.568 us; speedup 1.0000x reference)
//
#include <hip/hip_runtime.h>
#include <hip/hip_bf16.h>
#include <math.h>

#define D 4096
#define T 8192
#define R 512
#define HD 128
#define NH 32

typedef unsigned short u16;
typedef u16 u16x8 __attribute__((ext_vector_type(8)));
typedef __bf16 bf16x8 __attribute__((ext_vector_type(8)));
typedef float f32x4 __attribute__((ext_vector_type(4)));

__device__ __forceinline__ u16 f2bf(float f) {
  unsigned u = __builtin_bit_cast(unsigned, f);
  u += 0x7FFFu + ((u >> 16) & 1u);   // RNE
  return (u16)(u >> 16);
}
__device__ __forceinline__ float bf2f(u16 b) {
  return __builtin_bit_cast(float, ((unsigned)b) << 16);
}
__device__ __forceinline__ bf16x8 ldb8(const u16* p) {
  return __builtin_bit_cast(bf16x8, *(const u16x8*)p);
}
// async global->LDS, 16B per lane; LDS dest = wave-uniform base + lane*16
__device__ __forceinline__ void async_cp16(void* gsrc, void* ldst) {
  typedef __attribute__((address_space(1))) void gvoid;
  typedef __attribute__((address_space(3))) void lvoid;
  __builtin_amdgcn_global_load_lds((gvoid*)gsrc, (lvoid*)ldst, 16, 0, 0);
}
#define MFMA(a, b, c) __builtin_amdgcn_mfma_f32_16x16x32_bf16(a, b, c, 0, 0, 0)

// ---------------- LayerNorm (fp32 in -> bf16 out), one block per row ----------------
__global__ __launch_bounds__(256) void ln_bf16(
    const float* __restrict__ X, const float* __restrict__ w,
    const float* __restrict__ b, u16* __restrict__ out) {
  const int row = blockIdx.x, tid = threadIdx.x;
  const int lane = tid & 63, wv = tid >> 6;
  const float* xr = X + (long)row * D;
  float4 v[4];
  float s = 0.f, ss = 0.f;
#pragma unroll
  for (int i = 0; i < 4; ++i) {
    v[i] = *(const float4*)(xr + tid * 4 + i * 1024);
    s += v[i].x + v[i].y + v[i].z + v[i].w;
    ss += v[i].x * v[i].x + v[i].y * v[i].y + v[i].z * v[i].z + v[i].w * v[i].w;
  }
#pragma unroll
  for (int off = 32; off >= 1; off >>= 1) {
    s += __shfl_xor(s, off);
    ss += __shfl_xor(ss, off);
  }
  __shared__ float sw[4], ssw[4];
  if (lane == 0) { sw[wv] = s; ssw[wv] = ss; }
  __syncthreads();
  s = sw[0] + sw[1] + sw[2] + sw[3];
  ss = ssw[0] + ssw[1] + ssw[2] + ssw[3];
  const float mu = s * (1.f / D);
  const float var = ss * (1.f / D) - mu * mu;
  const float rstd = rsqrtf(var + 1e-5f);
#pragma unroll
  for (int i = 0; i < 4; ++i) {
    const int base = tid * 4 + i * 1024;
    const float4 wv4 = *(const float4*)(w + base);
    const float4 bv4 = *(const float4*)(b + base);
    ushort4 ov;
    ov.x = f2bf((v[i].x - mu) * rstd * wv4.x + bv4.x);
    ov.y = f2bf((v[i].y - mu) * rstd * wv4.y + bv4.y);
    ov.z = f2bf((v[i].z - mu) * rstd * wv4.z + bv4.z);
    ov.w = f2bf((v[i].w - mu) * rstd * wv4.w + bv4.w);
    *(ushort4*)(out + (long)row * D + base) = ov;
  }
}

// ------------- weight transpose + fp32->bf16 convert: W (K x N) -> Wt (N x K) -------------
__global__ __launch_bounds__(256) void wconv(const float* __restrict__ W,
                                             u16* __restrict__ Wt) {
  __shared__ float t[32][33];
  const int tx = threadIdx.x & 31, ty = threadIdx.x >> 5;
  const int n0 = blockIdx.x * 32, k0 = blockIdx.y * 32;
#pragma unroll
  for (int i = 0; i < 4; ++i)
    t[ty + i * 8][tx] = W[(long)(k0 + ty + i * 8) * D + n0 + tx];
  __syncthreads();
#pragma unroll
  for (int i = 0; i < 4; ++i)
    Wt[(long)(n0 + ty + i * 8) * D + k0 + tx] = f2bf(t[tx][ty + i * 8]);
}

// ---------------- GEMM C = A(MxK) * Bt(NxK)^T, K = D = 4096, bf16 MFMA ----------------
// EPI: 0 = bf16 store *scale; 1 = k/v split (v stored transposed);
//      2 = fp32 store acc + af;  3 = bf16 store gelu(acc);  4 = of += acc + bf2f(ab)
template <int EPI>
__global__ __launch_bounds__(256) void gemm_bt(
    const u16* __restrict__ A, const u16* __restrict__ Bt, u16* __restrict__ ob,
    u16* __restrict__ ob2, float* __restrict__ of, const float* __restrict__ af,
    const u16* __restrict__ ab, float scale) {
  __shared__ u16 As[128 * 32];
  __shared__ u16 Bs[128 * 32];
  const int tid = threadIdx.x;
  const int bx = blockIdx.x, by = blockIdx.y;  // bx: n-block, by: m-block
  const int lane = tid & 63, w = tid >> 6;
  const int ln15 = lane & 15, q = lane >> 4;
  const int wm = (w >> 1) * 64, wn = (w & 1) * 64;

  // staging: 512 16B-chunks per tile; chunk c -> row c>>2, 16B-slot c&3
  const int c0 = tid, c1 = tid + 256;
  const u16* ag0 = A + (long)(by * 128 + (c0 >> 2)) * D + (c0 & 3) * 8;
  const u16* ag1 = A + (long)(by * 128 + (c1 >> 2)) * D + (c1 & 3) * 8;
  const u16* bg0 = Bt + (long)(bx * 128 + (c0 >> 2)) * D + (c0 & 3) * 8;
  const u16* bg1 = Bt + (long)(bx * 128 + (c1 >> 2)) * D + (c1 & 3) * 8;
  u16* al0 = As + (tid & ~63) * 8;
  u16* al1 = As + ((tid & ~63) + 256) * 8;
  u16* bl0 = Bs + (tid & ~63) * 8;
  u16* bl1 = Bs + ((tid & ~63) + 256) * 8;

  f32x4 acc[4][4];
#pragma unroll
  for (int i = 0; i < 4; ++i)
#pragma unroll
    for (int j = 0; j < 4; ++j) {
      f32x4 z = {0.f, 0.f, 0.f, 0.f};
      acc[i][j] = z;
    }

  for (int k0 = 0; k0 < D; k0 += 32) {
    __syncthreads();
    async_cp16((void*)(ag0 + k0), al0);
    async_cp16((void*)(ag1 + k0), al1);
    async_cp16((void*)(bg0 + k0), bl0);
    async_cp16((void*)(bg1 + k0), bl1);
    __syncthreads();
    bf16x8 av[4], bv[4];
#pragma unroll
    for (int i = 0; i < 4; ++i) av[i] = ldb8(As + (wm + i * 16 + ln15) * 32 + q * 8);
#pragma unroll
    for (int j = 0; j < 4; ++j) bv[j] = ldb8(Bs + (wn + j * 16 + ln15) * 32 + q * 8);
#pragma unroll
    for (int i = 0; i < 4; ++i)
#pragma unroll
      for (int j = 0; j < 4; ++j) acc[i][j] = MFMA(av[i], bv[j], acc[i][j]);
  }

  // epilogue; C-layout: col = lane&15, row = quad*4 + reg
#pragma unroll
  for (int i = 0; i < 4; ++i) {
    const int gmb = by * 128 + wm + i * 16 + q * 4;
#pragma unroll
    for (int j = 0; j < 4; ++j) {
      const int gn = bx * 128 + wn + j * 16 + ln15;
#pragma unroll
      for (int r = 0; r < 4; ++r) {
        const int gm = gmb + r;
        const float vacc = acc[i][j][r];
        const long idx = (long)gm * D + gn;
        if constexpr (EPI == 0) {
          ob[idx] = f2bf(vacc * scale);
        } else if constexpr (EPI == 1) {
          if (gn < D)
            ob[idx] = f2bf(vacc);                       // k: (R x D)
          else
            ob2[(long)(gn - D) * R + gm] = f2bf(vacc);  // v^T: (D x R)
        } else if constexpr (EPI == 2) {
          of[idx] = vacc + af[idx];
        } else if constexpr (EPI == 3) {
          ob[idx] = f2bf(0.5f * vacc * (1.f + erff(vacc * 0.7071067811865475f)));
        } else {
          of[idx] = of[idx] + vacc + bf2f(ab[idx]);
        }
      }
    }
  }
}

// ---------------- fused cross-attention, online softmax ----------------
// block = (64 tokens, 1 head); Q pre-scaled by 1/sqrt(HD); O written in-place over Q.
__global__ __launch_bounds__(256) void attn_fused(const u16* Q,
                                                  const u16* __restrict__ Kb,
                                                  const u16* __restrict__ Vt,
                                                  u16* O) {
  __shared__ u16 Qs[64 * 136];   // pad 128->136 (16B mult, 2-way banks)
  __shared__ u16 Ks[64 * 136];
  __shared__ u16 Vs[128 * 72];   // V^T chunk: 128 hd x 64 latents, pad 64->72
  __shared__ u16 Ps[4][16 * 72]; // per-wave P round-trip
  const int tid = threadIdx.x;
  const int lane = tid & 63, w = tid >> 6;
  const int ln15 = lane & 15, q = lane >> 4;
  const int t0 = blockIdx.x * 64, h = blockIdx.y;

#pragma unroll
  for (int it = 0; it < 4; ++it) {
    const int c = tid + it * 256;
    const int row = c >> 4, cj = c & 15;
    *(u16x8*)(Qs + row * 136 + cj * 8) =
        *(const u16x8*)(Q + (long)(t0 + row) * D + h * HD + cj * 8);
  }

  f32x4 o[8];
  float m_run[4], l_run[4];
#pragma unroll
  for (int t = 0; t < 8; ++t) {
    f32x4 z = {0.f, 0.f, 0.f, 0.f};
    o[t] = z;
  }
#pragma unroll
  for (int r = 0; r < 4; ++r) {
    m_run[r] = -1e30f;
    l_run[r] = 0.f;
  }

  for (int ch = 0; ch < 8; ++ch) {
    const int r0 = ch * 64;
    __syncthreads();
#pragma unroll
    for (int it = 0; it < 4; ++it) {
      const int c = tid + it * 256;
      const int row = c >> 4, cj = c & 15;
      *(u16x8*)(Ks + row * 136 + cj * 8) =
          *(const u16x8*)(Kb + (long)(r0 + row) * D + h * HD + cj * 8);
    }
#pragma unroll
    for (int it = 0; it < 4; ++it) {
      const int c = tid + it * 256;
      const int hd = c >> 3, rj = c & 7;
      *(u16x8*)(Vs + hd * 72 + rj * 8) =
          *(const u16x8*)(Vt + (long)(h * HD + hd) * R + r0 + rj * 8);
    }
    __syncthreads();

    // S chunk: wave w owns tokens w*16..+15; N = 64 latents, K = 128
    f32x4 s[4];
#pragma unroll
    for (int j = 0; j < 4; ++j) {
      f32x4 z = {0.f, 0.f, 0.f, 0.f};
      s[j] = z;
    }
#pragma unroll
    for (int kk = 0; kk < 4; ++kk) {
      const bf16x8 a = ldb8(Qs + (w * 16 + ln15) * 136 + kk * 32 + q * 8);
#pragma unroll
      for (int j = 0; j < 4; ++j) {
        const bf16x8 b = ldb8(Ks + (j * 16 + ln15) * 136 + kk * 32 + q * 8);
        s[j] = MFMA(a, b, s[j]);
      }
    }
    // online softmax (rows q*4+r live in this quad's 16 lanes)
    float mx[4], rs[4];
#pragma unroll
    for (int r = 0; r < 4; ++r)
      mx[r] = fmaxf(fmaxf(s[0][r], s[1][r]), fmaxf(s[2][r], s[3][r]));
#pragma unroll
    for (int off = 8; off >= 1; off >>= 1)
#pragma unroll
      for (int r = 0; r < 4; ++r) mx[r] = fmaxf(mx[r], __shfl_xor(mx[r], off));
#pragma unroll
    for (int r = 0; r < 4; ++r) {
      const float mn = fmaxf(m_run[r], mx[r]);
      const float al = __expf(m_run[r] - mn);
      m_run[r] = mn;
      float a2 = 0.f;
#pragma unroll
      for (int j = 0; j < 4; ++j) {
        const float p = __expf(s[j][r] - mn);
        s[j][r] = p;
        a2 += p;
      }
      rs[r] = a2;
      l_run[r] *= al;
#pragma unroll
      for (int t = 0; t < 8; ++t) o[t][r] *= al;
    }
#pragma unroll
    for (int off = 8; off >= 1; off >>= 1)
#pragma unroll
      for (int r = 0; r < 4; ++r) rs[r] += __shfl_xor(rs[r], off);
#pragma unroll
    for (int r = 0; r < 4; ++r) l_run[r] += rs[r];
    // P -> LDS (C-layout regs -> row-major), then PV with A-layout reads
#pragma unroll
    for (int j = 0; j < 4; ++j)
#pragma unroll
      for (int r = 0; r < 4; ++r)
        Ps[w][(q * 4 + r) * 72 + j * 16 + ln15] = f2bf(s[j][r]);
    __syncthreads();
#pragma unroll
    for (int kk = 0; kk < 2; ++kk) {
      const bf16x8 a = ldb8(Ps[w] + ln15 * 72 + kk * 32 + q * 8);
#pragma unroll
      for (int t = 0; t < 8; ++t) {
        const bf16x8 b = ldb8(Vs + (t * 16 + ln15) * 72 + kk * 32 + q * 8);
        o[t] = MFMA(a, b, o[t]);
      }
    }
  }
#pragma unroll
  for (int r = 0; r < 4; ++r) l_run[r] = 1.f / l_run[r];
#pragma unroll
  for (int t = 0; t < 8; ++t)
#pragma unroll
    for (int r = 0; r < 4; ++r) {
      const int row = t0 + w * 16 + q * 4 + r;
      const int col = h * HD + t * 16 + ln15;
      O[(long)row * D + col] = f2bf(o[t][r] * l_run[r]);
    }
}

extern "C" void kernel_launch(void* const* d_in, const int* in_sizes, int n_in,
                              void* d_out, int out_size, void* d_ws, size_t ws_size,
                              hipStream_t stream) {
  (void)in_sizes; (void)n_in; (void)out_size;
  const float* x      = (const float*)d_in[0];
  const float* lat    = (const float*)d_in[2];
  const float* ln_q_w = (const float*)d_in[3];
  const float* ln_q_b = (const float*)d_in[4];
  const float* ln_c_w = (const float*)d_in[5];
  const float* ln_c_b = (const float*)d_in[6];
  const float* Wq     = (const float*)d_in[7];
  const float* Wk     = (const float*)d_in[8];
  const float* Wv     = (const float*)d_in[9];
  const float* Wo     = (const float*)d_in[10];
  const float* ln_m_w = (const float*)d_in[11];
  const float* ln_m_b = (const float*)d_in[12];
  const float* W1     = (const float*)d_in[13];
  const float* W2     = (const float*)d_in[14];
  float* out = (float*)d_out;

  const long DD = (long)D * D, TD = (long)T * D, RD = (long)R * D;
  u16* p = (u16*)d_ws;
  u16* Wt   = p; p += 2 * DD;   // transposed bf16 weights (reused slot)
  u16* a_bf = p; p += TD;       // LN output / y
  u16* q_bf = p; p += TD;       // q -> o (in-place) -> g
  u16* xc   = p; p += RD;
  u16* k_bf = p; p += RD;
  u16* v_t  = p; p += RD;       // V^T (D x R)
  if (ws_size < (size_t)(p - (u16*)d_ws) * sizeof(u16)) return;

  const dim3 B(256);
  const dim3 Gw(128, 128);      // wconv grid for 4096x4096
  const dim3 Gg(32, 64);        // GEMM: N=4096, M=8192

  ln_bf16<<<T, B, 0, stream>>>(x, ln_q_w, ln_q_b, a_bf);
  ln_bf16<<<R, B, 0, stream>>>(lat, ln_c_w, ln_c_b, xc);

  wconv<<<Gw, B, 0, stream>>>(Wq, Wt);
  gemm_bt<0><<<Gg, B, 0, stream>>>(a_bf, Wt, q_bf, nullptr, nullptr, nullptr,
                                   nullptr, 0.08838834764831845f);

  wconv<<<Gw, B, 0, stream>>>(Wk, Wt);
  wconv<<<Gw, B, 0, stream>>>(Wv, Wt + DD);
  gemm_bt<1><<<dim3(64, 4), B, 0, stream>>>(xc, Wt, k_bf, v_t, nullptr, nullptr,
                                            nullptr, 1.f);

  attn_fused<<<dim3(128, 32), B, 0, stream>>>(q_bf, k_bf, v_t, q_bf);

  wconv<<<Gw, B, 0, stream>>>(Wo, Wt);
  gemm_bt<2><<<Gg, B, 0, stream>>>(q_bf, Wt, nullptr, nullptr, out, x, nullptr, 1.f);

  ln_bf16<<<T, B, 0, stream>>>(out, ln_m_w, ln_m_b, a_bf);

  wconv<<<Gw, B, 0, stream>>>(W1, Wt);
  gemm_bt<3><<<Gg, B, 0, stream>>>(a_bf, Wt, q_bf, nullptr, nullptr, nullptr,
                                   nullptr, 1.f);

  wconv<<<Gw, B, 0, stream>>>(W2, Wt);
  gemm_bt<4><<<Gg, B, 0, stream>>>(q_bf, Wt, nullptr, nullptr, out, nullptr,
                                   a_bf, 1.f);
}